// Round 1
// 353.708 us; speedup vs baseline: 1.0186x; 1.0186x over previous
//
#include <hip/hip_runtime.h>
#include <hip/hip_bf16.h>

typedef __bf16 bf16_t;
typedef __bf16 bf16x8 __attribute__((ext_vector_type(8)));
typedef float  f32x4  __attribute__((ext_vector_type(4)));

#define MFMA16(A,B,C) __builtin_amdgcn_mfma_f32_16x16x32_bf16(A,B,C,0,0,0)

constexpr int HIDc = 4544;   // 142 k-steps of 32
constexpr int NHc  = 71;
constexpr int NHPc = 80;
constexpr int HDc  = 64;
constexpr int Uc   = 32;
constexpr int Sc   = 2048;
constexpr int RQ   = 4672;   // (71+2)*64

// ---- workspace layout (bytes) ----
constexpr size_t OFF_FUSED = 0;           // [32][4672] f32 = 598016
constexpr size_t OFF_QHI   = 598016;      // [32][80][64] bf16
constexpr size_t OFF_QLO   = 925696;
constexpr size_t OFF_KCUR  = 1253376;     // [32][64] f32
constexpr size_t OFF_VCUR  = 1261568;
constexpr size_t OFF_MP    = 1269760;     // [32][NPB<=16][71] f32 (max 145408)
constexpr size_t OFF_LP    = 1415168;
constexpr size_t OFF_AHI   = 1560576;     // [32][4544] bf16
constexpr size_t OFF_ALO   = 1851392;
constexpr size_t OFF_OP    = 2142208;     // [32][NPB][71][64] f32

// fp32 -> bf16x8 load (32B aligned)
__device__ __forceinline__ bf16x8 ld8f(const float* base, long eidx) {
  const float* p = base + eidx;
  const f32x4 a = *(const f32x4*)p;
  const f32x4 b = *(const f32x4*)(p + 4);
  bf16x8 r;
  r[0]=(bf16_t)a[0]; r[1]=(bf16_t)a[1]; r[2]=(bf16_t)a[2]; r[3]=(bf16_t)a[3];
  r[4]=(bf16_t)b[0]; r[5]=(bf16_t)b[1]; r[6]=(bf16_t)b[2]; r[7]=(bf16_t)b[3];
  return r;
}

// async global -> LDS copies (lds dest = wave-uniform base + lane*size)
__device__ __forceinline__ void cp16(const float* g, float* l) {
  __builtin_amdgcn_global_load_lds((const __attribute__((address_space(1))) void*)g,
                                   (__attribute__((address_space(3))) void*)l, 16, 0, 0);
}
__device__ __forceinline__ void cp4(const float* g, float* l) {
  __builtin_amdgcn_global_load_lds((const __attribute__((address_space(1))) void*)g,
                                   (__attribute__((address_space(3))) void*)l, 4, 0, 0);
}

// ---------------- zero fused + d_out ----------------
__global__ __launch_bounds__(256) void k_zeros(float* fused, float* out) {
  const int i = blockIdx.x*256 + threadIdx.x;       // grid 1152 -> 294912
  if (i < Uc*RQ) fused[i] = 0.f;
  else           out[i - Uc*RQ] = 0.f;              // Uc*HIDc elements
}

// ---------------- Kernel 1: QKV GEMM, grid (73,8), atomic reduce ----------------
__global__ __launch_bounds__(256) void k_qkv(
    const float* __restrict__ hidden, const float* __restrict__ wqkv,
    float* __restrict__ fused)
{
  const int h = blockIdx.x, y = blockIdx.y;
  const int t = threadIdx.x;
  const int wave = t >> 6, lane = t & 63;
  const int c = lane & 15, q4 = lane >> 4;
  const int mt = wave & 1, kh = wave >> 1;
  const int ks0 = y*18;
  const int ksn = min(18, 142 - ks0);     // y=7 gets 16
  const int h1  = ksn >> 1;
  const int kbeg = ks0 + (kh ? h1 : 0);
  const int kend = ks0 + (kh ? ksn : h1);
  __shared__ float sD[Uc*HDc];

  const long abase = (long)(mt*16 + c)*HIDc + q4*8;
  const long bbase = ((long)h*64 + c)*HIDc + q4*8;
  f32x4 acc[4] = {};
#pragma unroll 3
  for (int ks = kbeg; ks < kend; ++ks) {
    const bf16x8 af = ld8f(hidden, abase + ks*32);
#pragma unroll
    for (int nf = 0; nf < 4; ++nf) {
      const bf16x8 bv = ld8f(wqkv, bbase + (long)nf*16*HIDc + ks*32);
      acc[nf] = MFMA16(af, bv, acc[nf]);
    }
  }
  if (kh == 0) {
#pragma unroll
    for (int r = 0; r < 4; ++r)
#pragma unroll
      for (int nf = 0; nf < 4; ++nf)
        sD[(mt*16 + q4*4 + r)*64 + nf*16 + c] = acc[nf][r];
  }
  __syncthreads();
  if (kh == 1) {
#pragma unroll
    for (int r = 0; r < 4; ++r)
#pragma unroll
      for (int nf = 0; nf < 4; ++nf)
        sD[(mt*16 + q4*4 + r)*64 + nf*16 + c] += acc[nf][r];
  }
  __syncthreads();
  for (int i = t; i < Uc*HDc; i += 256)
    atomicAdd(&fused[(long)(i >> 6)*RQ + h*64 + (i & 63)], sD[i]);
}

// ---------------- Kernel 2: rotary + hi/lo split ----------------
__global__ __launch_bounds__(256) void k_rotary(
    const float* __restrict__ fused,
    const float* __restrict__ cosp, const float* __restrict__ sinp,
    bf16_t* __restrict__ qhi, bf16_t* __restrict__ qlo,
    float* __restrict__ kcur, float* __restrict__ vcur)
{
  const int h = blockIdx.x;    // 0..79
  const int t = threadIdx.x;
  __shared__ float sD[Uc*HDc];
  if (h < 73) {
    for (int i = t; i < Uc*HDc; i += 256)
      sD[i] = fused[(long)(i >> 6)*RQ + h*64 + (i & 63)];
    __syncthreads();
  }
  if (h >= NHc) {  // zero q pad rows 71..79
    for (int i = t; i < Uc*HDc; i += 256) {
      const long idx = (((long)(i >> 6))*NHPc + h)*HDc + (i & 63);
      qhi[idx] = (bf16_t)0.f;  qlo[idx] = (bf16_t)0.f;
    }
  }
  if (h >= 73) return;
  for (int i = t; i < Uc*HDc; i += 256) {
    const int u = i >> 6, d = i & 63;
    const float x = sD[i];
    const float partner = sD[i ^ 32];
    const float cs = cosp[u*HDc + d];
    const float sn = sinp[u*HDc + d];
    const float rh = (d < 32) ? -partner : partner;
    const float val = x*cs + rh*sn;
    if (h < NHc) {
      const long idx = ((long)u*NHPc + h)*HDc + d;
      const bf16_t hi = (bf16_t)val;
      qhi[idx] = hi;
      qlo[idx] = (bf16_t)(val - (float)hi);
    } else if (h == NHc) {
      kcur[u*HDc + d] = val;     // rotated shared K head
    } else {
      vcur[u*HDc + d] = x;       // V head: no rotary
    }
  }
}

// ---------------- Kernel 3: flash-decode partials, grid (32, NPB) ----------------
// Async LDS double-buffered K/V staging; shuffle-free PV via K-row permutation.
// Dynamic LDS layout (floats):
//   [0, 32768)      : stage, wave w at w*8192; buf b at b*4096; K +0, V +2048
//   [32768, 34816)  : masks, wave w at +w*512
//   [34816, 35136)  : sM [4][80]
//   [35136, 35456)  : sL [4][80]
//   sO [80*64] aliases [0, 5120)  (used only after the compute loop + barrier)
constexpr int ATTN_SMEM_FLOATS = 35456;
constexpr int ATTN_SMEM_BYTES  = ATTN_SMEM_FLOATS * 4;   // 141824

__global__ __launch_bounds__(256, 1) void k_attn(
    const float* __restrict__ kc, const float* __restrict__ vc,
    const float* __restrict__ masks,
    const bf16_t* __restrict__ qhi, const bf16_t* __restrict__ qlo,
    float* __restrict__ Mp, float* __restrict__ Lp, float* __restrict__ Op,
    const int NPB)
{
  extern __shared__ float smem[];
  const int u  = blockIdx.x;
  const int pb = blockIdx.y;
  const int tid = threadIdx.x;
  const int wave = __builtin_amdgcn_readfirstlane(tid >> 6);
  const int lane = tid & 63;
  const int c    = lane & 15;
  const int q4   = lane >> 4;
  const int pbpc = NPB >> 2;            // partial blocks per chunk
  const int keys_pb   = 2048 / pbpc;
  const int keys_wave = keys_pb >> 2;
  const int tcnt      = keys_wave >> 5;
  const int chunk = pb / pbpc;
  const int inner = pb - chunk*pbpc;
  const int s_base = inner*keys_pb + wave*keys_wave;
  const long kvbase = ((long)(chunk*Uc + u))*Sc;

  float* const wstage = smem + wave*8192;
  float* const mwave  = smem + 32768 + wave*512;
  float* const sM     = smem + 34816;   // [4][80]
  float* const sL     = smem + 35136;   // [4][80]
  float* const sO     = smem;           // alias, safe post-loop

  const int srow = lane >> 4;           // dest row within 4-row group
  const int scol = (lane & 15) << 2;    // dest d' base (f32 words)

  // ---- issue tile-0 K/V staging + all masks for this wave (async) ----
  {
    const long tb = (kvbase + s_base) * 64;
    const float* gK = kc + tb;
    const float* gV = vc + tb;
#pragma unroll
    for (int i = 0; i < 8; ++i) {
      const int row = i*4 + srow;
      const int fz = ((row & 7) << 2) ^ (((row >> 3) & 1) << 4);
      const int off = row*64 + (scol ^ fz);
      cp16(gK + off, wstage + i*256);
      cp16(gV + off, wstage + 2048 + i*256);
    }
    const int nmc = keys_wave >> 6;     // 2/4/8 for NPB 16/8/4
    const float* gM = masks + kvbase + s_base;
    for (int i = 0; i < nmc; ++i)
      cp4(gM + i*64 + lane, mwave + i*64);
  }

  // ---- Q fragments (hi/lo): B[k=d][n=head] ----
  bf16x8 qh[5][2], ql[5][2];
  const bf16_t* qb  = qhi + ((long)u*NHPc + c)*HDc + q4*8;
  const bf16_t* qb2 = qlo + ((long)u*NHPc + c)*HDc + q4*8;
#pragma unroll
  for (int ht = 0; ht < 5; ++ht)
#pragma unroll
    for (int ks = 0; ks < 2; ++ks) {
      qh[ht][ks] = *(const bf16x8*)(qb  + ht*16*HDc + ks*32);
      ql[ht][ks] = *(const bf16x8*)(qb2 + ht*16*HDc + ks*32);
    }

  float m_i[5], l_i[5];
  f32x4 Oa[5][4] = {};
#pragma unroll
  for (int ht = 0; ht < 5; ++ht) { m_i[ht] = -INFINITY; l_i[ht] = 0.f; }

  // K-row permutation so S^T C-layout == PV A-layout (zero shuffles):
  // A row m=c reads key krow0 + mt*4, krow0 = (c>>2)*8 + (c&3)
  const int krow0 = ((c >> 2) << 3) + (c & 3);

  for (int t = 0; t < tcnt; ++t) {
    float* const lK = wstage + (t & 1)*4096;
    float* const lV = lK + 2048;

    // prefetch next tile into other buffer, then wait for current tile only
    if (t + 1 < tcnt) {
      float* const nK = wstage + ((t+1) & 1)*4096;
      const long tb = (kvbase + s_base + (long)(t+1)*32) * 64;
      const float* gK = kc + tb;
      const float* gV = vc + tb;
#pragma unroll
      for (int i = 0; i < 8; ++i) {
        const int row = i*4 + srow;
        const int fz = ((row & 7) << 2) ^ (((row >> 3) & 1) << 4);
        const int off = row*64 + (scol ^ fz);
        cp16(gK + off, nK + i*256);
        cp16(gV + off, nK + 2048 + i*256);
      }
      asm volatile("s_waitcnt vmcnt(16)" ::: "memory");  // 16 newest = prefetch
    } else {
      asm volatile("s_waitcnt vmcnt(0)" ::: "memory");
    }
    __builtin_amdgcn_sched_barrier(0);

    // K A-fragments from LDS (swizzled, permuted rows)
    bf16x8 kf[2][2];
#pragma unroll
    for (int mt2 = 0; mt2 < 2; ++mt2) {
      const int row = krow0 + mt2*4;
      const int fz = ((row & 7) << 2) ^ (((row >> 3) & 1) << 4);
#pragma unroll
      for (int ks = 0; ks < 2; ++ks) {
        const int b0 = row*64 + ((ks*32 + q4*8) ^ fz);
        const int b1 = row*64 + ((ks*32 + q4*8 + 4) ^ fz);
        const f32x4 a = *(const f32x4*)(lK + b0);
        const f32x4 b = *(const f32x4*)(lK + b1);
        bf16x8 r;
        r[0]=(bf16_t)a[0]; r[1]=(bf16_t)a[1]; r[2]=(bf16_t)a[2]; r[3]=(bf16_t)a[3];
        r[4]=(bf16_t)b[0]; r[5]=(bf16_t)b[1]; r[6]=(bf16_t)b[2]; r[7]=(bf16_t)b[3];
        kf[mt2][ks] = r;
      }
    }

    // V B-fragments from LDS: B[k=key q4*8+j][n=dim dt*16+c]
    bf16x8 vf[4];
#pragma unroll
    for (int dt = 0; dt < 4; ++dt) {
      union { bf16_t e[8]; bf16x8 v; } uv;
#pragma unroll
      for (int j = 0; j < 8; ++j) {
        const int row = q4*8 + j;
        const int fz = ((row & 7) << 2) ^ (((row >> 3) & 1) << 4);
        uv.e[j] = (bf16_t)lV[row*64 + ((dt*16 + c) ^ fz)];
      }
      vf[dt] = uv.v;
    }

    // S^T tiles; slot (mt2, reg r, lane q4) holds key q4*8 + mt2*4 + r, head c
    f32x4 S[2][5];
#pragma unroll
    for (int mt2 = 0; mt2 < 2; ++mt2)
#pragma unroll
      for (int ht = 0; ht < 5; ++ht) {
        f32x4 s = {};
        s = MFMA16(kf[mt2][0], qh[ht][0], s);
        s = MFMA16(kf[mt2][1], qh[ht][1], s);
        s = MFMA16(kf[mt2][0], ql[ht][0], s);
        s = MFMA16(kf[mt2][1], ql[ht][1], s);
        S[mt2][ht] = s;
      }

    // scale + mask (mask matches permuted slot keys; broadcast LDS reads)
    float mk[2][4];
#pragma unroll
    for (int mt2 = 0; mt2 < 2; ++mt2)
#pragma unroll
      for (int r = 0; r < 4; ++r)
        mk[mt2][r] = mwave[t*32 + q4*8 + mt2*4 + r];
#pragma unroll
    for (int mt2 = 0; mt2 < 2; ++mt2)
#pragma unroll
      for (int ht = 0; ht < 5; ++ht)
#pragma unroll
        for (int r = 0; r < 4; ++r)
          S[mt2][ht][r] = S[mt2][ht][r]*0.125f + mk[mt2][r];

    // online softmax (head = lane&15 within tile ht); order-invariant over slots
    float alpha[5];
#pragma unroll
    for (int ht = 0; ht < 5; ++ht) {
      float tm = S[0][ht][0];
#pragma unroll
      for (int mt2 = 0; mt2 < 2; ++mt2)
#pragma unroll
        for (int r = 0; r < 4; ++r) tm = fmaxf(tm, S[mt2][ht][r]);
      tm = fmaxf(tm, __shfl_xor(tm, 16));
      tm = fmaxf(tm, __shfl_xor(tm, 32));
      const float mn = fmaxf(m_i[ht], tm);
      alpha[ht] = __expf(m_i[ht] - mn);
      m_i[ht] = mn;
    }
#pragma unroll
    for (int mt2 = 0; mt2 < 2; ++mt2)
#pragma unroll
      for (int ht = 0; ht < 5; ++ht)
#pragma unroll
        for (int r = 0; r < 4; ++r)
          S[mt2][ht][r] = __expf(S[mt2][ht][r] - m_i[ht]);
#pragma unroll
    for (int ht = 0; ht < 5; ++ht) {
      float rs = 0.f;
#pragma unroll
      for (int mt2 = 0; mt2 < 2; ++mt2)
#pragma unroll
        for (int r = 0; r < 4; ++r) rs += S[mt2][ht][r];
      rs += __shfl_xor(rs, 16);
      rs += __shfl_xor(rs, 32);
      l_i[ht] = l_i[ht]*alpha[ht] + rs;
    }
    // rescale O (O row head = q4*4+r)
#pragma unroll
    for (int ht = 0; ht < 5; ++ht)
#pragma unroll
      for (int r = 0; r < 4; ++r) {
        const float ar = __shfl(alpha[ht], q4*4 + r);
#pragma unroll
        for (int dt = 0; dt < 4; ++dt) Oa[ht][dt][r] *= ar;
      }
    // P A-fragments straight from S registers (zero shuffles):
    // A slot j = key q4*8+j = S[j>>2][reg j&3]
    bf16x8 ph[5], pl[5];
#pragma unroll
    for (int ht = 0; ht < 5; ++ht) {
      union { bf16_t e[8]; bf16x8 v; } uh, ul;
#pragma unroll
      for (int j = 0; j < 8; ++j) {
        const float val = (j < 4) ? S[0][ht][j] : S[1][ht][j & 3];
        const bf16_t hi = (bf16_t)val;
        uh.e[j] = hi;
        ul.e[j] = (bf16_t)(val - (float)hi);
      }
      ph[ht] = uh.v;  pl[ht] = ul.v;
    }
#pragma unroll
    for (int ht = 0; ht < 5; ++ht)
#pragma unroll
      for (int dt = 0; dt < 4; ++dt) {
        Oa[ht][dt] = MFMA16(ph[ht], vf[dt], Oa[ht][dt]);
        Oa[ht][dt] = MFMA16(pl[ht], vf[dt], Oa[ht][dt]);
      }
  }

  // ---- block-level combine of the 4 wave segments ----
  if (lane < 16)
#pragma unroll
    for (int ht = 0; ht < 5; ++ht) {
      sM[wave*80 + ht*16 + lane] = m_i[ht];
      sL[wave*80 + ht*16 + lane] = l_i[ht];
    }
  __syncthreads();
#pragma unroll
  for (int ht = 0; ht < 5; ++ht)
#pragma unroll
    for (int r = 0; r < 4; ++r) {
      const int hh = ht*16 + q4*4 + r;
      float mg = fmaxf(fmaxf(sM[hh], sM[80 + hh]), fmaxf(sM[160 + hh], sM[240 + hh]));
      mg = fmaxf(mg, -1e30f);
      const float aw = __expf(sM[wave*80 + hh] - mg);
#pragma unroll
      for (int dt = 0; dt < 4; ++dt) Oa[ht][dt][r] *= aw;
    }
  for (int w = 0; w < 4; ++w) {
    if (wave == w) {
#pragma unroll
      for (int ht = 0; ht < 5; ++ht)
#pragma unroll
        for (int dt = 0; dt < 4; ++dt)
#pragma unroll
          for (int r = 0; r < 4; ++r) {
            const int idx = (ht*16 + q4*4 + r)*HDc + dt*16 + c;
            if (w == 0) sO[idx] = Oa[ht][dt][r];
            else        sO[idx] += Oa[ht][dt][r];
          }
    }
    __syncthreads();
  }
  float* op = Op + ((long)u*NPB + pb)*NHc*HDc;
  for (int i = tid; i < NHc*HDc; i += 256) op[i] = sO[i];
  if (wave == 0 && lane < 16) {
#pragma unroll
    for (int ht = 0; ht < 5; ++ht) {
      const int hh = ht*16 + lane;
      if (hh < NHc) {
        float mg = fmaxf(fmaxf(sM[hh], sM[80 + hh]), fmaxf(sM[160 + hh], sM[240 + hh]));
        mg = fmaxf(mg, -1e30f);
        float L = 0.f;
#pragma unroll
        for (int w = 0; w < 4; ++w) L += __expf(sM[w*80 + hh] - mg)*sL[w*80 + hh];
        Mp[((long)u*NPB + pb)*NHc + hh] = mg;
        Lp[((long)u*NPB + pb)*NHc + hh] = L;
      }
    }
  }
}

// ---------------- Kernel 4: combine + current token, grid (71,32) ----------------
__global__ __launch_bounds__(64) void k_combine(
    const float* __restrict__ Mp, const float* __restrict__ Lp,
    const float* __restrict__ Op,
    const bf16_t* __restrict__ qhi, const bf16_t* __restrict__ qlo,
    const float* __restrict__ kcur, const float* __restrict__ vcur,
    bf16_t* __restrict__ ahi, bf16_t* __restrict__ alo, const int NPB)
{
  const int h = blockIdx.x, u = blockIdx.y;
  const int lane = threadIdx.x;   // = d
  const long qidx = ((long)u*NHPc + h)*HDc + lane;
  float pr = ((float)qhi[qidx] + (float)qlo[qidx]) * kcur[u*HDc + lane];
#pragma unroll
  for (int o = 32; o > 0; o >>= 1) pr += __shfl_xor(pr, o);
  const float s_cur = pr * 0.125f;

  float g = s_cur;
  for (int p = 0; p < NPB; ++p)
    g = fmaxf(g, Mp[((long)u*NPB + p)*NHc + h]);
  g = fmaxf(g, -1e30f);
  float sw = 0.f, acc = 0.f;
  const float* ob = Op + (long)u*NPB*NHc*HDc + (long)h*HDc + lane;
  for (int p = 0; p < NPB; ++p) {
    const float f = __expf(Mp[((long)u*NPB + p)*NHc + h] - g);
    sw += f*Lp[((long)u*NPB + p)*NHc + h];
    acc += f*ob[(long)p*NHc*HDc];
  }
  const float cw = __expf(s_cur - g);
  acc += cw * vcur[u*HDc + lane];
  const float attn = acc / (sw + cw);
  const bf16_t hi = (bf16_t)attn;
  ahi[(long)u*HIDc + h*HDc + lane] = hi;
  alo[(long)u*HIDc + h*HDc + lane] = (bf16_t)(attn - (float)hi);
}

// ---------------- Kernel 5: dense GEMM, grid (142,8), atomic reduce ----------------
__global__ __launch_bounds__(256) void k_outgemm(
    const bf16_t* __restrict__ ahi, const bf16_t* __restrict__ alo,
    const float* __restrict__ wd, float* __restrict__ out)
{
  const int nb = blockIdx.x, y = blockIdx.y;
  const int t = threadIdx.x;
  const int wave = t >> 6, lane = t & 63;
  const int c = lane & 15, q4 = lane >> 4;
  const int mt = wave & 1, kh = wave >> 1;
  const int ks0 = y*18;
  const int ksn = min(18, 142 - ks0);
  const int h1  = ksn >> 1;
  const int kbeg = ks0 + (kh ? h1 : 0);
  const int kend = ks0 + (kh ? ksn : h1);
  __shared__ float sC[Uc*32];

  const bf16_t* aph = ahi + ((long)(mt*16 + c))*HIDc + q4*8;
  const bf16_t* apl = alo + ((long)(mt*16 + c))*HIDc + q4*8;
  const long bbase = ((long)nb*32 + c)*HIDc + q4*8;

  f32x4 acc[2] = {};
#pragma unroll 3
  for (int ks = kbeg; ks < kend; ++ks) {
    const bf16x8 Ah = *(const bf16x8*)(aph + ks*32);
    const bf16x8 Al = *(const bf16x8*)(apl + ks*32);
#pragma unroll
    for (int nf = 0; nf < 2; ++nf) {
      const bf16x8 B = ld8f(wd, bbase + (long)nf*16*HIDc + ks*32);
      acc[nf] = MFMA16(Ah, B, acc[nf]);
      acc[nf] = MFMA16(Al, B, acc[nf]);
    }
  }
  if (kh == 0) {
#pragma unroll
    for (int r = 0; r < 4; ++r)
#pragma unroll
      for (int nf = 0; nf < 2; ++nf)
        sC[(mt*16 + q4*4 + r)*32 + nf*16 + c] = acc[nf][r];
  }
  __syncthreads();
  if (kh == 1) {
#pragma unroll
    for (int r = 0; r < 4; ++r)
#pragma unroll
      for (int nf = 0; nf < 2; ++nf)
        sC[(mt*16 + q4*4 + r)*32 + nf*16 + c] += acc[nf][r];
  }
  __syncthreads();
  for (int i = t; i < Uc*32; i += 256)
    atomicAdd(&out[(long)(i >> 5)*HIDc + nb*32 + (i & 31)], sC[i]);
}

extern "C" void kernel_launch(void* const* d_in, const int* in_sizes, int n_in,
                              void* d_out, int out_size, void* d_ws, size_t ws_size,
                              hipStream_t stream)
{
  const float* hidden = (const float*)d_in[0];
  const float* cosp   = (const float*)d_in[1];
  const float* sinp   = (const float*)d_in[2];
  const float* kcache = (const float*)d_in[3];
  const float* vcache = (const float*)d_in[4];
  const float* masks  = (const float*)d_in[5];
  const float* wqkv   = (const float*)d_in[6];
  const float* wdense = (const float*)d_in[7];
  float* out = (float*)d_out;

  // pick NPB (flash partials per user) by available workspace
  const size_t opb = (size_t)Uc*NHc*HDc*4;
  int NPB = 16;
  if      (ws_size >= OFF_OP + 16*opb) NPB = 16;
  else if (ws_size >= OFF_OP +  8*opb) NPB = 8;
  else if (ws_size >= OFF_OP +  4*opb) NPB = 4;
  else return;

  char* ws = (char*)d_ws;
  float*  fused = (float*)(ws + OFF_FUSED);
  bf16_t* qhi   = (bf16_t*)(ws + OFF_QHI);
  bf16_t* qlo   = (bf16_t*)(ws + OFF_QLO);
  float*  kcur  = (float*)(ws + OFF_KCUR);
  float*  vcur  = (float*)(ws + OFF_VCUR);
  float*  Mp    = (float*)(ws + OFF_MP);
  float*  Lp    = (float*)(ws + OFF_LP);
  bf16_t* ahi   = (bf16_t*)(ws + OFF_AHI);
  bf16_t* alo   = (bf16_t*)(ws + OFF_ALO);
  float*  Op    = (float*)(ws + OFF_OP);

  // allow >64KB dynamic LDS for k_attn (gfx950: 160KB/WG)
  hipFuncSetAttribute(reinterpret_cast<const void*>(k_attn),
                      hipFuncAttributeMaxDynamicSharedMemorySize, ATTN_SMEM_BYTES);

  k_zeros  <<<1152, 256, 0, stream>>>(fused, out);
  k_qkv    <<<dim3(73, 8), 256, 0, stream>>>(hidden, wqkv, fused);
  k_rotary <<<80, 256, 0, stream>>>(fused, cosp, sinp, qhi, qlo, kcur, vcur);
  k_attn   <<<dim3(32, NPB), 256, ATTN_SMEM_BYTES, stream>>>(kcache, vcache, masks, qhi, qlo, Mp, Lp, Op, NPB);
  k_combine<<<dim3(71, 32), 64, 0, stream>>>(Mp, Lp, Op, qhi, qlo, kcur, vcur, ahi, alo, NPB);
  k_outgemm<<<dim3(142, 8), 256, 0, stream>>>(ahi, alo, wdense, out);
}

// Round 2
// 334.725 us; speedup vs baseline: 1.0764x; 1.0567x over previous
//
#include <hip/hip_runtime.h>
#include <hip/hip_bf16.h>

typedef __bf16 bf16_t;
typedef __bf16 bf16x8 __attribute__((ext_vector_type(8)));
typedef float  f32x4  __attribute__((ext_vector_type(4)));

#define MFMA16(A,B,C) __builtin_amdgcn_mfma_f32_16x16x32_bf16(A,B,C,0,0,0)

constexpr int HIDc = 4544;   // 142 k-steps of 32
constexpr int NHc  = 71;
constexpr int NHPc = 80;
constexpr int HDc  = 64;
constexpr int Uc   = 32;
constexpr int Sc   = 2048;
constexpr int RQ   = 4672;   // (71+2)*64

// ---- workspace layout (bytes) ----
constexpr size_t OFF_FUSED = 0;           // [32][4672] f32 = 598016
constexpr size_t OFF_QHI   = 598016;      // [32][80][64] bf16
constexpr size_t OFF_QLO   = 925696;
constexpr size_t OFF_KCUR  = 1253376;     // [32][64] f32
constexpr size_t OFF_VCUR  = 1261568;
constexpr size_t OFF_MP    = 1269760;     // [32][NPB<=16][71] f32 (max 145408)
constexpr size_t OFF_LP    = 1415168;
constexpr size_t OFF_AHI   = 1560576;     // [32][4544] bf16
constexpr size_t OFF_ALO   = 1851392;
constexpr size_t OFF_OP    = 2142208;     // [32][NPB][71][64] f32

// fp32 -> bf16x8 load (32B aligned)
__device__ __forceinline__ bf16x8 ld8f(const float* base, long eidx) {
  const float* p = base + eidx;
  const f32x4 a = *(const f32x4*)p;
  const f32x4 b = *(const f32x4*)(p + 4);
  bf16x8 r;
  r[0]=(bf16_t)a[0]; r[1]=(bf16_t)a[1]; r[2]=(bf16_t)a[2]; r[3]=(bf16_t)a[3];
  r[4]=(bf16_t)b[0]; r[5]=(bf16_t)b[1]; r[6]=(bf16_t)b[2]; r[7]=(bf16_t)b[3];
  return r;
}

// async global -> LDS copies (lds dest = wave-uniform base + lane*size)
__device__ __forceinline__ void cp16(const float* g, float* l) {
  __builtin_amdgcn_global_load_lds((const __attribute__((address_space(1))) void*)g,
                                   (__attribute__((address_space(3))) void*)l, 16, 0, 0);
}
__device__ __forceinline__ void cp4(const float* g, float* l) {
  __builtin_amdgcn_global_load_lds((const __attribute__((address_space(1))) void*)g,
                                   (__attribute__((address_space(3))) void*)l, 4, 0, 0);
}

// ---------------- zero fused + d_out ----------------
__global__ __launch_bounds__(256) void k_zeros(float* fused, float* out) {
  const int i = blockIdx.x*256 + threadIdx.x;       // grid 1152 -> 294912
  if (i < Uc*RQ) fused[i] = 0.f;
  else           out[i - Uc*RQ] = 0.f;              // Uc*HIDc elements
}

// ---------------- Kernel 1: QKV GEMM, grid (73,8), atomic reduce ----------------
__global__ __launch_bounds__(256) void k_qkv(
    const float* __restrict__ hidden, const float* __restrict__ wqkv,
    float* __restrict__ fused)
{
  const int h = blockIdx.x, y = blockIdx.y;
  const int t = threadIdx.x;
  const int wave = t >> 6, lane = t & 63;
  const int c = lane & 15, q4 = lane >> 4;
  const int mt = wave & 1, kh = wave >> 1;
  const int ks0 = y*18;
  const int ksn = min(18, 142 - ks0);     // y=7 gets 16
  const int h1  = ksn >> 1;
  const int kbeg = ks0 + (kh ? h1 : 0);
  const int kend = ks0 + (kh ? ksn : h1);
  __shared__ float sD[Uc*HDc];

  const long abase = (long)(mt*16 + c)*HIDc + q4*8;
  const long bbase = ((long)h*64 + c)*HIDc + q4*8;
  f32x4 acc[4] = {};
#pragma unroll 3
  for (int ks = kbeg; ks < kend; ++ks) {
    const bf16x8 af = ld8f(hidden, abase + ks*32);
#pragma unroll
    for (int nf = 0; nf < 4; ++nf) {
      const bf16x8 bv = ld8f(wqkv, bbase + (long)nf*16*HIDc + ks*32);
      acc[nf] = MFMA16(af, bv, acc[nf]);
    }
  }
  if (kh == 0) {
#pragma unroll
    for (int r = 0; r < 4; ++r)
#pragma unroll
      for (int nf = 0; nf < 4; ++nf)
        sD[(mt*16 + q4*4 + r)*64 + nf*16 + c] = acc[nf][r];
  }
  __syncthreads();
  if (kh == 1) {
#pragma unroll
    for (int r = 0; r < 4; ++r)
#pragma unroll
      for (int nf = 0; nf < 4; ++nf)
        sD[(mt*16 + q4*4 + r)*64 + nf*16 + c] += acc[nf][r];
  }
  __syncthreads();
  for (int i = t; i < Uc*HDc; i += 256)
    atomicAdd(&fused[(long)(i >> 6)*RQ + h*64 + (i & 63)], sD[i]);
}

// ---------------- Kernel 2: rotary + hi/lo split ----------------
__global__ __launch_bounds__(256) void k_rotary(
    const float* __restrict__ fused,
    const float* __restrict__ cosp, const float* __restrict__ sinp,
    bf16_t* __restrict__ qhi, bf16_t* __restrict__ qlo,
    float* __restrict__ kcur, float* __restrict__ vcur)
{
  const int h = blockIdx.x;    // 0..79
  const int t = threadIdx.x;
  __shared__ float sD[Uc*HDc];
  if (h < 73) {
    for (int i = t; i < Uc*HDc; i += 256)
      sD[i] = fused[(long)(i >> 6)*RQ + h*64 + (i & 63)];
    __syncthreads();
  }
  if (h >= NHc) {  // zero q pad rows 71..79
    for (int i = t; i < Uc*HDc; i += 256) {
      const long idx = (((long)(i >> 6))*NHPc + h)*HDc + (i & 63);
      qhi[idx] = (bf16_t)0.f;  qlo[idx] = (bf16_t)0.f;
    }
  }
  if (h >= 73) return;
  for (int i = t; i < Uc*HDc; i += 256) {
    const int u = i >> 6, d = i & 63;
    const float x = sD[i];
    const float partner = sD[i ^ 32];
    const float cs = cosp[u*HDc + d];
    const float sn = sinp[u*HDc + d];
    const float rh = (d < 32) ? -partner : partner;
    const float val = x*cs + rh*sn;
    if (h < NHc) {
      const long idx = ((long)u*NHPc + h)*HDc + d;
      const bf16_t hi = (bf16_t)val;
      qhi[idx] = hi;
      qlo[idx] = (bf16_t)(val - (float)hi);
    } else if (h == NHc) {
      kcur[u*HDc + d] = val;     // rotated shared K head
    } else {
      vcur[u*HDc + d] = x;       // V head: no rotary
    }
  }
}

// ---------------- Kernel 3: flash-decode partials, grid (32, NPB) ----------------
// Cooperative producer/consumer block: 8 waves (512 thr).
//   waves 0-4 : consumers, wave = head-tile ht (16 heads each, NHP=80)
//   wave 5    : K producer (8 x cp16 per 32-key tile)
//   wave 6    : V producer (8 x cp16 per 32-key tile)
//   wave 7    : mask producer (prologue only)
// 4-deep circular LDS tile buffer, counted per-wave vmcnt (depth-3 in flight).
// 2 barriers per tile: B1 = slot (t+3)&3 free, B2 = tile t ready.
// Consumers use __syncthreads (their vmcnt is empty -> free); producers use raw
// s_barrier + counted vmcnt so prefetches stay in flight across barriers.
// LDS floats: stage 4*4096 (slot: K 2048 | V 2048), masks up to 2048.
constexpr int ATTN_SLOT_F   = 4096;
constexpr int ATTN_STAGE_F  = 4*ATTN_SLOT_F;            // 16384
constexpr int ATTN_SMEM_F   = ATTN_STAGE_F + 2048;      // 18432
constexpr int ATTN_SMEM_BYTES = ATTN_SMEM_F * 4;        // 73728 -> 2 blocks/CU

__global__ __launch_bounds__(512, 4) void k_attn(
    const float* __restrict__ kc, const float* __restrict__ vc,
    const float* __restrict__ masks,
    const bf16_t* __restrict__ qhi, const bf16_t* __restrict__ qlo,
    float* __restrict__ Mp, float* __restrict__ Lp, float* __restrict__ Op,
    const int NPB)
{
  extern __shared__ float smem[];
  const int u  = blockIdx.x;
  const int pb = blockIdx.y;
  const int tid = threadIdx.x;
  const int wave = __builtin_amdgcn_readfirstlane(tid >> 6);
  const int lane = tid & 63;
  const int c    = lane & 15;
  const int q4   = lane >> 4;
  const int pbpc = NPB >> 2;            // partial blocks per chunk
  const int keys_pb = 2048 / pbpc;      // keys per block
  const int tcnt    = keys_pb >> 5;     // 32-key tiles
  const int chunk = pb / pbpc;
  const int inner = pb - chunk*pbpc;
  const int s_base = inner*keys_pb;
  const long kvbase = ((long)(chunk*Uc + u))*Sc;

  float* const stage = smem;
  float* const smask = smem + ATTN_STAGE_F;

  const int srow = lane >> 4;           // dest row within 4-row group
  const int scol = (lane & 15) << 2;    // dest d' base (f32 words)

  if (wave >= 5) {
    // ================= producer path =================
    if (wave == 7) {
      const int nmc = keys_pb >> 6;
      const float* gM = masks + kvbase + s_base;
      for (int i = 0; i < nmc; ++i)
        cp4(gM + i*64 + lane, smask + i*64);
      for (int t = 0; t < tcnt; ++t) {
        __builtin_amdgcn_s_barrier();                       // B1
        if (t == 0) asm volatile("s_waitcnt vmcnt(0)" ::: "memory");
        __builtin_amdgcn_s_barrier();                       // B2
      }
      return;
    }
    const float* gsrc = (wave == 5) ? kc : vc;
    const int vofs = (wave == 6) ? 2048 : 0;
    // prologue: tiles 0..2 into slots 0..2
    for (int pt = 0; pt < 3; ++pt) {
      const long tb = (kvbase + s_base + pt*32) * 64;
      float* dst = stage + pt*ATTN_SLOT_F + vofs;
#pragma unroll
      for (int i = 0; i < 8; ++i) {
        const int row = i*4 + srow;
        const int fz = ((row & 7) << 2) ^ (((row >> 3) & 1) << 4);
        cp16(gsrc + tb + row*64 + (scol ^ fz), dst + i*256);
      }
    }
    for (int t = 0; t < tcnt; ++t) {
      __builtin_amdgcn_s_barrier();                         // B1: slot (t+3)&3 free
      if (t + 3 < tcnt) {
        const long tb = (kvbase + s_base + (long)(t+3)*32) * 64;
        float* dst = stage + ((t+3)&3)*ATTN_SLOT_F + vofs;
#pragma unroll
        for (int i = 0; i < 8; ++i) {
          const int row = i*4 + srow;
          const int fz = ((row & 7) << 2) ^ (((row >> 3) & 1) << 4);
          cp16(gsrc + tb + row*64 + (scol ^ fz), dst + i*256);
        }
      }
      const int rem = min(3, tcnt - 1 - t);   // own tiles still outstanding incl t
      if      (rem >= 3) asm volatile("s_waitcnt vmcnt(24)" ::: "memory");
      else if (rem == 2) asm volatile("s_waitcnt vmcnt(16)" ::: "memory");
      else if (rem == 1) asm volatile("s_waitcnt vmcnt(8)"  ::: "memory");
      else               asm volatile("s_waitcnt vmcnt(0)"  ::: "memory");
      __builtin_amdgcn_s_barrier();                         // B2: tile t ready
    }
    return;
  }

  // ================= consumer path (wave = ht, 16 heads) =================
  const int ht = wave;
  bf16x8 qh[2], ql[2];
  {
    const bf16_t* qb  = qhi + ((long)u*NHPc + ht*16 + c)*HDc + q4*8;
    const bf16_t* qb2 = qlo + ((long)u*NHPc + ht*16 + c)*HDc + q4*8;
#pragma unroll
    for (int ks = 0; ks < 2; ++ks) {
      qh[ks] = *(const bf16x8*)(qb  + ks*32);
      ql[ks] = *(const bf16x8*)(qb2 + ks*32);
    }
  }

  float m_i = -INFINITY, l_i = 0.f;
  f32x4 Oa[4] = {};

  // K-row permutation so S^T C-layout == PV A-layout (zero shuffles):
  // A row m=c reads key krow0 + mt2*4, krow0 = (c>>2)*8 + (c&3)
  const int krow0 = ((c >> 2) << 3) + (c & 3);

  for (int t = 0; t < tcnt; ++t) {
    __syncthreads();                                        // B1
    __syncthreads();                                        // B2: tile t ready
    float* const lK = stage + (t & 3)*ATTN_SLOT_F;
    float* const lV = lK + 2048;

    // K A-fragments from LDS (swizzled, permuted rows)
    bf16x8 kf[2][2];
#pragma unroll
    for (int mt2 = 0; mt2 < 2; ++mt2) {
      const int row = krow0 + mt2*4;
      const int fz = ((row & 7) << 2) ^ (((row >> 3) & 1) << 4);
#pragma unroll
      for (int ks = 0; ks < 2; ++ks) {
        const int b0 = row*64 + ((ks*32 + q4*8) ^ fz);
        const int b1 = row*64 + ((ks*32 + q4*8 + 4) ^ fz);
        const f32x4 a = *(const f32x4*)(lK + b0);
        const f32x4 b = *(const f32x4*)(lK + b1);
        bf16x8 r;
        r[0]=(bf16_t)a[0]; r[1]=(bf16_t)a[1]; r[2]=(bf16_t)a[2]; r[3]=(bf16_t)a[3];
        r[4]=(bf16_t)b[0]; r[5]=(bf16_t)b[1]; r[6]=(bf16_t)b[2]; r[7]=(bf16_t)b[3];
        kf[mt2][ks] = r;
      }
    }

    // V B-fragments from LDS: B[k=key q4*8+j][n=dim dt*16+c]
    bf16x8 vf[4];
#pragma unroll
    for (int dt = 0; dt < 4; ++dt) {
      union { bf16_t e[8]; bf16x8 v; } uv;
#pragma unroll
      for (int j = 0; j < 8; ++j) {
        const int row = q4*8 + j;
        const int fz = ((row & 7) << 2) ^ (((row >> 3) & 1) << 4);
        uv.e[j] = (bf16_t)lV[row*64 + ((dt*16 + c) ^ fz)];
      }
      vf[dt] = uv.v;
    }

    // S^T tiles; slot (mt2, reg r, lane q4) holds key q4*8 + mt2*4 + r, head c
    f32x4 S[2];
#pragma unroll
    for (int mt2 = 0; mt2 < 2; ++mt2) {
      f32x4 s = {};
      s = MFMA16(kf[mt2][0], qh[0], s);
      s = MFMA16(kf[mt2][1], qh[1], s);
      s = MFMA16(kf[mt2][0], ql[0], s);
      s = MFMA16(kf[mt2][1], ql[1], s);
      S[mt2] = s;
    }

    // scale + mask (mask matches permuted slot keys; broadcast LDS reads)
#pragma unroll
    for (int mt2 = 0; mt2 < 2; ++mt2)
#pragma unroll
      for (int r = 0; r < 4; ++r)
        S[mt2][r] = S[mt2][r]*0.125f + smask[t*32 + q4*8 + mt2*4 + r];

    // online softmax (head = lane&15); order-invariant over slots
    float tm = S[0][0];
#pragma unroll
    for (int mt2 = 0; mt2 < 2; ++mt2)
#pragma unroll
      for (int r = 0; r < 4; ++r) tm = fmaxf(tm, S[mt2][r]);
    tm = fmaxf(tm, __shfl_xor(tm, 16));
    tm = fmaxf(tm, __shfl_xor(tm, 32));
    const float mn = fmaxf(m_i, tm);
    const float alpha = __expf(m_i - mn);
    m_i = mn;
#pragma unroll
    for (int mt2 = 0; mt2 < 2; ++mt2)
#pragma unroll
      for (int r = 0; r < 4; ++r)
        S[mt2][r] = __expf(S[mt2][r] - m_i);
    float rs = 0.f;
#pragma unroll
    for (int mt2 = 0; mt2 < 2; ++mt2)
#pragma unroll
      for (int r = 0; r < 4; ++r) rs += S[mt2][r];
    rs += __shfl_xor(rs, 16);
    rs += __shfl_xor(rs, 32);
    l_i = l_i*alpha + rs;

    // rescale O (O row head = q4*4+r)
#pragma unroll
    for (int r = 0; r < 4; ++r) {
      const float ar = __shfl(alpha, q4*4 + r);
#pragma unroll
      for (int dt = 0; dt < 4; ++dt) Oa[dt][r] *= ar;
    }
    // P A-fragments straight from S registers (zero shuffles):
    // A slot j = key q4*8+j = S[j>>2][reg j&3]
    bf16x8 ph, pl;
    {
      union { bf16_t e[8]; bf16x8 v; } uh, ul;
#pragma unroll
      for (int j = 0; j < 8; ++j) {
        const float val = (j < 4) ? S[0][j] : S[1][j & 3];
        const bf16_t hi = (bf16_t)val;
        uh.e[j] = hi;
        ul.e[j] = (bf16_t)(val - (float)hi);
      }
      ph = uh.v;  pl = ul.v;
    }
#pragma unroll
    for (int dt = 0; dt < 4; ++dt) {
      Oa[dt] = MFMA16(ph, vf[dt], Oa[dt]);
      Oa[dt] = MFMA16(pl, vf[dt], Oa[dt]);
    }
  }

  // ---- direct epilogue: this wave owns heads ht*16 .. ht*16+15 ----
  float* op = Op + ((long)u*NPB + pb)*NHc*HDc;
#pragma unroll
  for (int dt = 0; dt < 4; ++dt)
#pragma unroll
    for (int r = 0; r < 4; ++r) {
      const int h = ht*16 + q4*4 + r;
      if (h < NHc) op[h*HDc + dt*16 + c] = Oa[dt][r];
    }
  if (q4 == 0) {
    const int hh = ht*16 + c;
    if (hh < NHc) {
      Mp[((long)u*NPB + pb)*NHc + hh] = fmaxf(m_i, -1e30f);
      Lp[((long)u*NPB + pb)*NHc + hh] = l_i;
    }
  }
}

// ---------------- Kernel 4: combine + current token, grid (71,32) ----------------
__global__ __launch_bounds__(64) void k_combine(
    const float* __restrict__ Mp, const float* __restrict__ Lp,
    const float* __restrict__ Op,
    const bf16_t* __restrict__ qhi, const bf16_t* __restrict__ qlo,
    const float* __restrict__ kcur, const float* __restrict__ vcur,
    bf16_t* __restrict__ ahi, bf16_t* __restrict__ alo, const int NPB)
{
  const int h = blockIdx.x, u = blockIdx.y;
  const int lane = threadIdx.x;   // = d
  const long qidx = ((long)u*NHPc + h)*HDc + lane;
  float pr = ((float)qhi[qidx] + (float)qlo[qidx]) * kcur[u*HDc + lane];
#pragma unroll
  for (int o = 32; o > 0; o >>= 1) pr += __shfl_xor(pr, o);
  const float s_cur = pr * 0.125f;

  float g = s_cur;
  for (int p = 0; p < NPB; ++p)
    g = fmaxf(g, Mp[((long)u*NPB + p)*NHc + h]);
  g = fmaxf(g, -1e30f);
  float sw = 0.f, acc = 0.f;
  const float* ob = Op + (long)u*NPB*NHc*HDc + (long)h*HDc + lane;
  for (int p = 0; p < NPB; ++p) {
    const float f = __expf(Mp[((long)u*NPB + p)*NHc + h] - g);
    sw += f*Lp[((long)u*NPB + p)*NHc + h];
    acc += f*ob[(long)p*NHc*HDc];
  }
  const float cw = __expf(s_cur - g);
  acc += cw * vcur[u*HDc + lane];
  const float attn = acc / (sw + cw);
  const bf16_t hi = (bf16_t)attn;
  ahi[(long)u*HIDc + h*HDc + lane] = hi;
  alo[(long)u*HIDc + h*HDc + lane] = (bf16_t)(attn - (float)hi);
}

// ---------------- Kernel 5: dense GEMM, grid (142,8), atomic reduce ----------------
__global__ __launch_bounds__(256) void k_outgemm(
    const bf16_t* __restrict__ ahi, const bf16_t* __restrict__ alo,
    const float* __restrict__ wd, float* __restrict__ out)
{
  const int nb = blockIdx.x, y = blockIdx.y;
  const int t = threadIdx.x;
  const int wave = t >> 6, lane = t & 63;
  const int c = lane & 15, q4 = lane >> 4;
  const int mt = wave & 1, kh = wave >> 1;
  const int ks0 = y*18;
  const int ksn = min(18, 142 - ks0);
  const int h1  = ksn >> 1;
  const int kbeg = ks0 + (kh ? h1 : 0);
  const int kend = ks0 + (kh ? ksn : h1);
  __shared__ float sC[Uc*32];

  const bf16_t* aph = ahi + ((long)(mt*16 + c))*HIDc + q4*8;
  const bf16_t* apl = alo + ((long)(mt*16 + c))*HIDc + q4*8;
  const long bbase = ((long)nb*32 + c)*HIDc + q4*8;

  f32x4 acc[2] = {};
#pragma unroll 3
  for (int ks = kbeg; ks < kend; ++ks) {
    const bf16x8 Ah = *(const bf16x8*)(aph + ks*32);
    const bf16x8 Al = *(const bf16x8*)(apl + ks*32);
#pragma unroll
    for (int nf = 0; nf < 2; ++nf) {
      const bf16x8 B = ld8f(wd, bbase + (long)nf*16*HIDc + ks*32);
      acc[nf] = MFMA16(Ah, B, acc[nf]);
      acc[nf] = MFMA16(Al, B, acc[nf]);
    }
  }
  if (kh == 0) {
#pragma unroll
    for (int r = 0; r < 4; ++r)
#pragma unroll
      for (int nf = 0; nf < 2; ++nf)
        sC[(mt*16 + q4*4 + r)*32 + nf*16 + c] = acc[nf][r];
  }
  __syncthreads();
  if (kh == 1) {
#pragma unroll
    for (int r = 0; r < 4; ++r)
#pragma unroll
      for (int nf = 0; nf < 2; ++nf)
        sC[(mt*16 + q4*4 + r)*32 + nf*16 + c] += acc[nf][r];
  }
  __syncthreads();
  for (int i = t; i < Uc*32; i += 256)
    atomicAdd(&out[(long)(i >> 5)*HIDc + nb*32 + (i & 31)], sC[i]);
}

extern "C" void kernel_launch(void* const* d_in, const int* in_sizes, int n_in,
                              void* d_out, int out_size, void* d_ws, size_t ws_size,
                              hipStream_t stream)
{
  const float* hidden = (const float*)d_in[0];
  const float* cosp   = (const float*)d_in[1];
  const float* sinp   = (const float*)d_in[2];
  const float* kcache = (const float*)d_in[3];
  const float* vcache = (const float*)d_in[4];
  const float* masks  = (const float*)d_in[5];
  const float* wqkv   = (const float*)d_in[6];
  const float* wdense = (const float*)d_in[7];
  float* out = (float*)d_out;

  // pick NPB (flash partials per user) by available workspace
  const size_t opb = (size_t)Uc*NHc*HDc*4;
  int NPB = 16;
  if      (ws_size >= OFF_OP + 16*opb) NPB = 16;
  else if (ws_size >= OFF_OP +  8*opb) NPB = 8;
  else if (ws_size >= OFF_OP +  4*opb) NPB = 4;
  else return;

  char* ws = (char*)d_ws;
  float*  fused = (float*)(ws + OFF_FUSED);
  bf16_t* qhi   = (bf16_t*)(ws + OFF_QHI);
  bf16_t* qlo   = (bf16_t*)(ws + OFF_QLO);
  float*  kcur  = (float*)(ws + OFF_KCUR);
  float*  vcur  = (float*)(ws + OFF_VCUR);
  float*  Mp    = (float*)(ws + OFF_MP);
  float*  Lp    = (float*)(ws + OFF_LP);
  bf16_t* ahi   = (bf16_t*)(ws + OFF_AHI);
  bf16_t* alo   = (bf16_t*)(ws + OFF_ALO);
  float*  Op    = (float*)(ws + OFF_OP);

  // allow >64KB dynamic LDS for k_attn (gfx950: 160KB/CU, 2 blocks/CU here)
  hipFuncSetAttribute(reinterpret_cast<const void*>(k_attn),
                      hipFuncAttributeMaxDynamicSharedMemorySize, ATTN_SMEM_BYTES);

  k_zeros  <<<1152, 256, 0, stream>>>(fused, out);
  k_qkv    <<<dim3(73, 8), 256, 0, stream>>>(hidden, wqkv, fused);
  k_rotary <<<80, 256, 0, stream>>>(fused, cosp, sinp, qhi, qlo, kcur, vcur);
  k_attn   <<<dim3(32, NPB), 512, ATTN_SMEM_BYTES, stream>>>(kcache, vcache, masks, qhi, qlo, Mp, Lp, Op, NPB);
  k_combine<<<dim3(71, 32), 64, 0, stream>>>(Mp, Lp, Op, qhi, qlo, kcur, vcur, ahi, alo, NPB);
  k_outgemm<<<dim3(142, 8), 256, 0, stream>>>(ahi, alo, wdense, out);
}